// Round 22
// baseline (612.404 us; speedup 1.0000x reference)
//
#include <hip/hip_runtime.h>
#include <math.h>

#define NROWS (512 * 512)
#define KCB   1024
#define DDIM  64
#define NQ    ((size_t)NROWS * DDIM)
#define RPW   64            // rows per wave (4 mt tiles) — one codebook sweep/wave
#define CMAX  6             // candidate cap per row
#define WAVES 16
#define BLKT  1024
#define NBLK  256           // 1 block per CU, persistent

typedef __attribute__((ext_vector_type(8))) short bf16x8;
typedef __attribute__((ext_vector_type(4))) float f32x4;

__device__ __forceinline__ unsigned short f2bf(float x) {
    unsigned u = __float_as_uint(x);
    u = u + 0x7FFFu + ((u >> 16) & 1u);
    return (unsigned short)(u >> 16);
}

// ---------- K1: frozen wsq + w->bf16 + wmax ----------
__global__ __launch_bounds__(1024)
void prep_w(const float* __restrict__ w, float* __restrict__ bsq,
            unsigned short* __restrict__ wbf, float* __restrict__ wmaxp) {
    __shared__ float red[16];
    const int k = threadIdx.x;
    const float* row = w + (size_t)k * DDIM;
    float r[8];
#pragma unroll
    for (int j = 0; j < 8; ++j) r[j] = __fmul_rn(row[j], row[j]);
#pragma unroll
    for (int i = 8; i < DDIM; i += 8)
#pragma unroll
        for (int j = 0; j < 8; ++j)
            r[j] = __fadd_rn(r[j], __fmul_rn(row[i + j], row[i + j]));
    float b = __fadd_rn(__fadd_rn(__fadd_rn(r[0], r[1]), __fadd_rn(r[2], r[3])),
                        __fadd_rn(__fadd_rn(r[4], r[5]), __fadd_rn(r[6], r[7])));
    bsq[k] = b;
    unsigned* dst = (unsigned*)(wbf + (size_t)k * DDIM);
#pragma unroll
    for (int j = 0; j < 32; ++j)
        dst[j] = (unsigned)f2bf(row[2 * j]) | ((unsigned)f2bf(row[2 * j + 1]) << 16);
    float v = sqrtf(b) * 1.02f;
#pragma unroll
    for (int off = 1; off < 64; off <<= 1) v = fmaxf(v, __shfl_xor(v, off));
    if ((threadIdx.x & 63) == 0) red[threadIdx.x >> 6] = v;
    __syncthreads();
    if (threadIdx.x == 0) {
        float m = red[0];
#pragma unroll
        for (int j = 1; j < 16; ++j) m = fmaxf(m, red[j]);
        *wmaxp = m;
    }
}

// ---------- K3: persistent blocks, codebook in LDS, RPW=64 single sweep ----------
__global__ __launch_bounds__(BLKT, 1)
void vq_scan(const float* __restrict__ h, const float* __restrict__ w,
             const unsigned short* __restrict__ wbf, const float* __restrict__ bsq,
             const float* __restrict__ wmaxp, float* __restrict__ out) {
    // full codebook, swizzled: row lr (0..1023) x 8 float4 chunks;
    // chunk c stored at s4[lr*8 + (c ^ (lr&7))]  (XOR involution, 16B granularity)
    __shared__ float4 s4[KCB * 8];                       // 131072 B
    __shared__ float smb[KCB];                           //   4096 B: -bsq/2 (scan only)
    __shared__ int scnt[WAVES][RPW];                     //   4096 B
    __shared__ unsigned short sclist[WAVES][RPW][CMAX];  //  12288 B
    __shared__ unsigned int sbk[WAVES][RPW];             //   4096 B  => 155648 total

    const int tid = threadIdx.x;
    const int wv = tid >> 6, lane = tid & 63;
    const int l16 = lane & 15, lh = lane >> 4;
    const size_t rowbase = ((size_t)blockIdx.x * WAVES + wv) * RPW;   // wave's 64 rows

    // ---- one-time stage: whole codebook, linear LDS write + inverse-permuted read ----
    {
        const float4* g4 = reinterpret_cast<const float4*>(wbf);
#pragma unroll
        for (int j = 0; j < 8; ++j) {
            int F = j * BLKT + tid;          // 0..8191
            int r = F >> 3, c = F & 7;
            s4[F] = g4[r * 8 + (c ^ (r & 7))];
        }
        smb[tid] = __fmul_rn(bsq[tid], -0.5f);   // C-in value: acc' = dot - bq/2
    }
    scnt[wv][lane] = 0;
    __syncthreads();   // the only block barrier

    // per-lane constant swizzled chunk indices (lr ≡ l16 mod 8)
    const int sw = l16 & 7;
    const int C0 = lh ^ sw;         // chunk for d0..31
    const int C1 = (4 + lh) ^ sw;   // chunk for d32..63
    const float wmaxv = *wmaxp;

    // Af: frozen pairwise-8 — lane r computes row r (all 64 lanes active)
    float af;
    {
        const float* row = h + (size_t)(rowbase + lane) * DDIM;
        float hr[DDIM];
#pragma unroll
        for (int i = 0; i < DDIM; i += 4) {
            float4 v = *reinterpret_cast<const float4*>(row + i);
            hr[i] = v.x; hr[i + 1] = v.y; hr[i + 2] = v.z; hr[i + 3] = v.w;
        }
        float s[8];
#pragma unroll
        for (int j = 0; j < 8; ++j) s[j] = __fmul_rn(hr[j], hr[j]);
#pragma unroll
        for (int i = 8; i < DDIM; i += 8)
#pragma unroll
            for (int j = 0; j < 8; ++j)
                s[j] = __fadd_rn(s[j], __fmul_rn(hr[i + j], hr[i + j]));
        af = __fadd_rn(__fadd_rn(__fadd_rn(s[0], s[1]), __fadd_rn(s[2], s[3])),
                       __fadd_rn(__fadd_rn(s[4], s[5]), __fadd_rn(s[6], s[7])));
    }

    // A-frags (h rows, bf16) — 4 mt tiles (R18-validated indexing)
    bf16x8 afr[4][2];
#pragma unroll
    for (int mt = 0; mt < 4; ++mt) {
        const float* hrow = h + ((size_t)(rowbase + mt * 16 + l16)) * DDIM;
#pragma unroll
        for (int dh = 0; dh < 2; ++dh) {
            float4 a = *reinterpret_cast<const float4*>(hrow + dh * 32 + lh * 8);
            float4 bq = *reinterpret_cast<const float4*>(hrow + dh * 32 + lh * 8 + 4);
            union { bf16x8 v; unsigned short u[8]; } pk;
            pk.u[0] = f2bf(a.x); pk.u[1] = f2bf(a.y); pk.u[2] = f2bf(a.z); pk.u[3] = f2bf(a.w);
            pk.u[4] = f2bf(bq.x); pk.u[5] = f2bf(bq.y); pk.u[6] = f2bf(bq.z); pk.u[7] = f2bf(bq.w);
            afr[mt][dh] = pk.v;
        }
    }

    // ---- PASS A: max-space; acc' = dot - bq/2 via MFMA C-in; 1 fmax/val ----
    float pmax[16];
#pragma unroll
    for (int j = 0; j < 16; ++j) pmax[j] = -INFINITY;

#pragma unroll 1
    for (int ch = 0; ch < 8; ++ch) {
        float4 cb0[8], cb1[8];
        float cmb[8];
#pragma unroll
        for (int t = 0; t < 8; ++t) {
            const int lr = (ch * 8 + t) * 16 + l16;
            cb0[t] = s4[lr * 8 + C0];
            cb1[t] = s4[lr * 8 + C1];
            cmb[t] = smb[lr];
        }
#pragma unroll
        for (int t = 0; t < 8; ++t) {
            bf16x8 bfr0 = *reinterpret_cast<const bf16x8*>(&cb0[t]);
            bf16x8 bfr1 = *reinterpret_cast<const bf16x8*>(&cb1[t]);
            f32x4 acc0 = {cmb[t], cmb[t], cmb[t], cmb[t]};
#pragma unroll
            for (int mt = 0; mt < 4; ++mt) {
                f32x4 acc = acc0;
                acc = __builtin_amdgcn_mfma_f32_16x16x32_bf16(afr[mt][0], bfr0, acc, 0, 0, 0);
                acc = __builtin_amdgcn_mfma_f32_16x16x32_bf16(afr[mt][1], bfr1, acc, 0, 0, 0);
#pragma unroll
                for (int i = 0; i < 4; ++i)
                    pmax[mt * 4 + i] = fmaxf(pmax[mt * 4 + i], acc[i]);
            }
        }
    }

    // butterfly max over the 16 l16-lanes; thresholds (validated margin, /2 in max space)
#pragma unroll
    for (int off = 1; off < 16; off <<= 1)
#pragma unroll
        for (int j = 0; j < 16; ++j) pmax[j] = fmaxf(pmax[j], __shfl_xor(pmax[j], off));
    float trA[16];
#pragma unroll
    for (int mt = 0; mt < 4; ++mt)
#pragma unroll
        for (int i = 0; i < 4; ++i) {
            float Afr = __shfl(af, mt * 16 + lh * 4 + i);
            trA[mt * 4 + i] = pmax[mt * 4 + i]
                            - (sqrtf(Afr) * 1.001f * wmaxv * 0.015625f + 5e-4f);
        }

    // ---- PASS B: candidates (recompute acc'; bitwise == pass A; push acc' >= trA) ----
#pragma unroll 1
    for (int ch = 0; ch < 8; ++ch) {
        float4 cb0[8], cb1[8];
        float cmb[8];
#pragma unroll
        for (int t = 0; t < 8; ++t) {
            const int lr = (ch * 8 + t) * 16 + l16;
            cb0[t] = s4[lr * 8 + C0];
            cb1[t] = s4[lr * 8 + C1];
            cmb[t] = smb[lr];
        }
#pragma unroll
        for (int t = 0; t < 8; ++t) {
            bf16x8 bfr0 = *reinterpret_cast<const bf16x8*>(&cb0[t]);
            bf16x8 bfr1 = *reinterpret_cast<const bf16x8*>(&cb1[t]);
            f32x4 acc0 = {cmb[t], cmb[t], cmb[t], cmb[t]};
            const int kk = (ch * 8 + t) * 16 + l16;
#pragma unroll
            for (int mt = 0; mt < 4; ++mt) {
                f32x4 acc = acc0;
                acc = __builtin_amdgcn_mfma_f32_16x16x32_bf16(afr[mt][0], bfr0, acc, 0, 0, 0);
                acc = __builtin_amdgcn_mfma_f32_16x16x32_bf16(afr[mt][1], bfr1, acc, 0, 0, 0);
#pragma unroll
                for (int i = 0; i < 4; ++i) {
                    if (acc[i] >= trA[mt * 4 + i]) {
                        int row = mt * 16 + lh * 4 + i;
                        int slot = atomicAdd(&scnt[wv][row], 1);
                        if (slot < CMAX) sclist[wv][row][slot] = (unsigned short)kk;
                    }
                }
            }
        }
    }
    __builtin_amdgcn_wave_barrier();

    // ---- rescore: lane r owns row r; sequential lexicographic (d,k) min ----
    {
        const int cnt = scnt[wv][lane];
        if (cnt <= CMAX) {
            const size_t ng = rowbase + lane;
            const float* hrow = h + ng * DDIM;
            float hreg[DDIM];
#pragma unroll
            for (int i = 0; i < DDIM; i += 4) {
                float4 v = *reinterpret_cast<const float4*>(hrow + i);
                hreg[i] = v.x; hreg[i + 1] = v.y; hreg[i + 2] = v.z; hreg[i + 3] = v.w;
            }
            float dbest = INFINITY;
            int kbest = 0x7FFFFFFF;
            for (int slot = 0; slot < cnt; ++slot) {
                int k = sclist[wv][lane][slot];
                const float* wr = w + (size_t)k * DDIM;
                float acc = 0.f;
#pragma unroll
                for (int i = 0; i < DDIM; i += 4) {
                    float4 x = *reinterpret_cast<const float4*>(wr + i);
                    acc = fmaf(hreg[i + 0], x.x, acc);
                    acc = fmaf(hreg[i + 1], x.y, acc);
                    acc = fmaf(hreg[i + 2], x.z, acc);
                    acc = fmaf(hreg[i + 3], x.w, acc);
                }
                float d = __fsub_rn(__fadd_rn(af, bsq[k]), __fadd_rn(acc, acc));
                if (d < dbest || (d == dbest && k < kbest)) { dbest = d; kbest = k; }
            }
            sbk[wv][lane] = (unsigned)kbest;
        }
    }
    // overflow fallback: wave-wide exact scan + in-wave lexicographic butterfly (rare)
#pragma unroll 1
    for (int r = 0; r < RPW; ++r) {
        if (scnt[wv][r] > CMAX) {
            const float Afr = __shfl(af, r);
            const size_t ng = rowbase + r;
            const float* hrow = h + ng * DDIM;
            float hreg[DDIM];
#pragma unroll
            for (int i = 0; i < DDIM; i += 4) {
                float4 v = *reinterpret_cast<const float4*>(hrow + i);
                hreg[i] = v.x; hreg[i + 1] = v.y; hreg[i + 2] = v.z; hreg[i + 3] = v.w;
            }
            float dbest = INFINITY;
            int kbest = 0x7FFFFFFF;
            for (int k = lane; k < KCB; k += 64) {
                const float* wr = w + (size_t)k * DDIM;
                float acc = 0.f;
#pragma unroll
                for (int i = 0; i < DDIM; i += 4) {
                    float4 x = *reinterpret_cast<const float4*>(wr + i);
                    acc = fmaf(hreg[i + 0], x.x, acc);
                    acc = fmaf(hreg[i + 1], x.y, acc);
                    acc = fmaf(hreg[i + 2], x.z, acc);
                    acc = fmaf(hreg[i + 3], x.w, acc);
                }
                float d = __fsub_rn(__fadd_rn(Afr, bsq[k]), __fadd_rn(acc, acc));
                if (d < dbest || (d == dbest && k < kbest)) { dbest = d; kbest = k; }
            }
#pragma unroll
            for (int off = 1; off < 64; off <<= 1) {
                float od = __shfl_xor(dbest, off);
                int ok = __shfl_xor(kbest, off);
                bool take = (od < dbest) || (od == dbest && ok < kbest);
                dbest = take ? od : dbest;
                kbest = take ? ok : kbest;
            }
            if (lane == 0) sbk[wv][r] = (unsigned)kbest;
        }
    }
    __builtin_amdgcn_wave_barrier();

    // ---- fused outputs (per wave) — frozen math, R18 lane layout ----
    out[NQ + rowbase + lane] = (float)sbk[wv][lane];

    // qst: 64 rows x 16 float4 = 16 per lane; ops identical to validated K4
#pragma unroll
    for (int q = 0; q < 16; ++q) {
        const int idx = q * 64 + lane;          // 0..1023
        const int row = idx >> 4, c4 = idx & 15;
        const int bk = (int)sbk[wv][row];
        const size_t ng = rowbase + row;
        float4 hq = *reinterpret_cast<const float4*>(h + ng * DDIM + 4 * c4);
        float4 wq = *reinterpret_cast<const float4*>(w + (size_t)bk * DDIM + 4 * c4);
        float4 o;
        o.x = __fadd_rn(hq.x, __fsub_rn(wq.x, hq.x));
        o.y = __fadd_rn(hq.y, __fsub_rn(wq.y, hq.y));
        o.z = __fadd_rn(hq.z, __fsub_rn(wq.z, hq.z));
        o.w = __fadd_rn(hq.w, __fsub_rn(wq.w, hq.w));
        *reinterpret_cast<float4*>(out + ng * DDIM + 4 * c4) = o;
    }

    // loss: all 64 lanes, one row each — verbatim frozen recipe (validated R2)
    {
        const int bk = (int)sbk[wv][lane];
        const size_t ng = rowbase + lane;
        const float* hrow = h + ng * DDIM;
        const float* qrow = w + (size_t)bk * DDIM;
        float hr[DDIM];
#pragma unroll
        for (int i = 0; i < DDIM; i += 4) {
            float4 v = *reinterpret_cast<const float4*>(hrow + i);
            hr[i] = v.x; hr[i + 1] = v.y; hr[i + 2] = v.z; hr[i + 3] = v.w;
        }
        float r2[8];
#pragma unroll
        for (int c = 0; c < 8; ++c) {
            float4 qa = *reinterpret_cast<const float4*>(qrow + 8 * c);
            float4 qb = *reinterpret_cast<const float4*>(qrow + 8 * c + 4);
            float d0 = __fsub_rn(qa.x, hr[8 * c + 0]);
            float d1 = __fsub_rn(qa.y, hr[8 * c + 1]);
            float d2 = __fsub_rn(qa.z, hr[8 * c + 2]);
            float d3 = __fsub_rn(qa.w, hr[8 * c + 3]);
            float d4 = __fsub_rn(qb.x, hr[8 * c + 4]);
            float d5 = __fsub_rn(qb.y, hr[8 * c + 5]);
            float d6 = __fsub_rn(qb.z, hr[8 * c + 6]);
            float d7 = __fsub_rn(qb.w, hr[8 * c + 7]);
            if (c == 0) {
                r2[0] = __fmul_rn(d0, d0); r2[1] = __fmul_rn(d1, d1);
                r2[2] = __fmul_rn(d2, d2); r2[3] = __fmul_rn(d3, d3);
                r2[4] = __fmul_rn(d4, d4); r2[5] = __fmul_rn(d5, d5);
                r2[6] = __fmul_rn(d6, d6); r2[7] = __fmul_rn(d7, d7);
            } else {
                r2[0] = __fadd_rn(r2[0], __fmul_rn(d0, d0));
                r2[1] = __fadd_rn(r2[1], __fmul_rn(d1, d1));
                r2[2] = __fadd_rn(r2[2], __fmul_rn(d2, d2));
                r2[3] = __fadd_rn(r2[3], __fmul_rn(d3, d3));
                r2[4] = __fadd_rn(r2[4], __fmul_rn(d4, d4));
                r2[5] = __fadd_rn(r2[5], __fmul_rn(d5, d5));
                r2[6] = __fadd_rn(r2[6], __fmul_rn(d6, d6));
                r2[7] = __fadd_rn(r2[7], __fmul_rn(d7, d7));
            }
        }
        float S = __fadd_rn(__fadd_rn(__fadd_rn(r2[0], r2[1]), __fadd_rn(r2[2], r2[3])),
                            __fadd_rn(__fadd_rn(r2[4], r2[5]), __fadd_rn(r2[6], r2[7])));
        float m = __fmul_rn(S, 0.015625f);
        out[NQ + NROWS + ng] = __fadd_rn(__fmul_rn(m, 0.1f), __fmul_rn(m, 0.2f));
    }
}

extern "C" void kernel_launch(void* const* d_in, const int* in_sizes, int n_in,
                              void* d_out, int out_size, void* d_ws, size_t ws_size,
                              hipStream_t stream) {
    (void)in_sizes; (void)n_in; (void)out_size; (void)ws_size;
    const float* h = (const float*)d_in[0];
    const float* w = (const float*)d_in[1];
    float* out = (float*)d_out;

    char* ws = (char*)d_ws;
    float* bsq = (float*)ws;                               // 4 KB
    float* wmaxp = (float*)(ws + 4096);                    // 16 B
    unsigned short* wbf = (unsigned short*)(ws + 8192);    // 128 KB

    prep_w<<<1, 1024, 0, stream>>>(w, bsq, wbf, wmaxp);
    vq_scan<<<NBLK, BLKT, 0, stream>>>(h, w, wbf, bsq, wmaxp, out);
}

// Round 23
// 475.597 us; speedup vs baseline: 1.2877x; 1.2877x over previous
//
#include <hip/hip_runtime.h>
#include <math.h>

#define NROWS (512 * 512)
#define KCB   1024
#define DDIM  64
#define NQ    ((size_t)NROWS * DDIM)
#define RPW   64            // rows per wave (4 mt tiles) — one codebook sweep/wave
#define CMAX  6             // candidate cap per row
#define WAVES 16
#define BLKT  1024
#define NBLK  256           // 1 block per CU, persistent
#define CHUNK 4             // tiles per chunk (8 ds_read_b128 in flight)
#define NCH   (KCB / 16 / CHUNK)   // 16 chunks

typedef __attribute__((ext_vector_type(8))) short bf16x8;
typedef __attribute__((ext_vector_type(4))) float f32x4;

__device__ __forceinline__ unsigned short f2bf(float x) {
    unsigned u = __float_as_uint(x);
    u = u + 0x7FFFu + ((u >> 16) & 1u);
    return (unsigned short)(u >> 16);
}

// ---------- K1: frozen wsq + w->bf16 + wmax ----------
__global__ __launch_bounds__(1024)
void prep_w(const float* __restrict__ w, float* __restrict__ bsq,
            unsigned short* __restrict__ wbf, float* __restrict__ wmaxp) {
    __shared__ float red[16];
    const int k = threadIdx.x;
    const float* row = w + (size_t)k * DDIM;
    float r[8];
#pragma unroll
    for (int j = 0; j < 8; ++j) r[j] = __fmul_rn(row[j], row[j]);
#pragma unroll
    for (int i = 8; i < DDIM; i += 8)
#pragma unroll
        for (int j = 0; j < 8; ++j)
            r[j] = __fadd_rn(r[j], __fmul_rn(row[i + j], row[i + j]));
    float b = __fadd_rn(__fadd_rn(__fadd_rn(r[0], r[1]), __fadd_rn(r[2], r[3])),
                        __fadd_rn(__fadd_rn(r[4], r[5]), __fadd_rn(r[6], r[7])));
    bsq[k] = b;
    unsigned* dst = (unsigned*)(wbf + (size_t)k * DDIM);
#pragma unroll
    for (int j = 0; j < 32; ++j)
        dst[j] = (unsigned)f2bf(row[2 * j]) | ((unsigned)f2bf(row[2 * j + 1]) << 16);
    float v = sqrtf(b) * 1.02f;
#pragma unroll
    for (int off = 1; off < 64; off <<= 1) v = fmaxf(v, __shfl_xor(v, off));
    if ((threadIdx.x & 63) == 0) red[threadIdx.x >> 6] = v;
    __syncthreads();
    if (threadIdx.x == 0) {
        float m = red[0];
#pragma unroll
        for (int j = 1; j < 16; ++j) m = fmaxf(m, red[j]);
        *wmaxp = m;
    }
}

// ---------- K3: persistent blocks, codebook in LDS, RPW=64, explicit 4 waves/EU ----------
__global__ __launch_bounds__(BLKT, 4)
void vq_scan(const float* __restrict__ h, const float* __restrict__ w,
             const unsigned short* __restrict__ wbf, const float* __restrict__ bsq,
             const float* __restrict__ wmaxp, float* __restrict__ out) {
    // full codebook, swizzled: row lr (0..1023) x 8 float4 chunks;
    // chunk c stored at s4[lr*8 + (c ^ (lr&7))]  (XOR involution, 16B granularity)
    __shared__ float4 s4[KCB * 8];                       // 131072 B
    __shared__ float smb[KCB];                           //   4096 B: -bsq/2 (scan only)
    __shared__ int scnt[WAVES][RPW];                     //   4096 B
    __shared__ unsigned short sclist[WAVES][RPW][CMAX];  //  12288 B
    __shared__ unsigned int sbk[WAVES][RPW];             //   4096 B  => 155648 total

    const int tid = threadIdx.x;
    const int wv = tid >> 6, lane = tid & 63;
    const int l16 = lane & 15, lh = lane >> 4;
    const size_t rowbase = ((size_t)blockIdx.x * WAVES + wv) * RPW;   // wave's 64 rows

    // ---- one-time stage: whole codebook, linear LDS write + inverse-permuted read ----
    {
        const float4* g4 = reinterpret_cast<const float4*>(wbf);
#pragma unroll
        for (int j = 0; j < 8; ++j) {
            int F = j * BLKT + tid;          // 0..8191
            int r = F >> 3, c = F & 7;
            s4[F] = g4[r * 8 + (c ^ (r & 7))];
        }
        smb[tid] = __fmul_rn(bsq[tid], -0.5f);   // C-in value: acc' = dot - bq/2
    }
    scnt[wv][lane] = 0;
    __syncthreads();   // the only block barrier

    // per-lane constant swizzled chunk indices (lr ≡ l16 mod 8)
    const int sw = l16 & 7;
    const int C0 = lh ^ sw;         // chunk for d0..31
    const int C1 = (4 + lh) ^ sw;   // chunk for d32..63
    const float wmaxv = *wmaxp;

    // Af: frozen pairwise-8 — lane r computes row r (all 64 lanes active)
    float af;
    {
        const float* row = h + (size_t)(rowbase + lane) * DDIM;
        float hr[DDIM];
#pragma unroll
        for (int i = 0; i < DDIM; i += 4) {
            float4 v = *reinterpret_cast<const float4*>(row + i);
            hr[i] = v.x; hr[i + 1] = v.y; hr[i + 2] = v.z; hr[i + 3] = v.w;
        }
        float s[8];
#pragma unroll
        for (int j = 0; j < 8; ++j) s[j] = __fmul_rn(hr[j], hr[j]);
#pragma unroll
        for (int i = 8; i < DDIM; i += 8)
#pragma unroll
            for (int j = 0; j < 8; ++j)
                s[j] = __fadd_rn(s[j], __fmul_rn(hr[i + j], hr[i + j]));
        af = __fadd_rn(__fadd_rn(__fadd_rn(s[0], s[1]), __fadd_rn(s[2], s[3])),
                       __fadd_rn(__fadd_rn(s[4], s[5]), __fadd_rn(s[6], s[7])));
    }

    // A-frags (h rows, bf16) — 4 mt tiles (R18/R22-validated indexing)
    bf16x8 afr[4][2];
#pragma unroll
    for (int mt = 0; mt < 4; ++mt) {
        const float* hrow = h + ((size_t)(rowbase + mt * 16 + l16)) * DDIM;
#pragma unroll
        for (int dh = 0; dh < 2; ++dh) {
            float4 a = *reinterpret_cast<const float4*>(hrow + dh * 32 + lh * 8);
            float4 bq = *reinterpret_cast<const float4*>(hrow + dh * 32 + lh * 8 + 4);
            union { bf16x8 v; unsigned short u[8]; } pk;
            pk.u[0] = f2bf(a.x); pk.u[1] = f2bf(a.y); pk.u[2] = f2bf(a.z); pk.u[3] = f2bf(a.w);
            pk.u[4] = f2bf(bq.x); pk.u[5] = f2bf(bq.y); pk.u[6] = f2bf(bq.z); pk.u[7] = f2bf(bq.w);
            afr[mt][dh] = pk.v;
        }
    }

    // ---- PASS A: max-space; acc' = dot - bq/2 via MFMA C-in; 1 fmax/val ----
    float pmax[16];
#pragma unroll
    for (int j = 0; j < 16; ++j) pmax[j] = -INFINITY;

#pragma unroll 1
    for (int ch = 0; ch < NCH; ++ch) {
        float4 cb0[CHUNK], cb1[CHUNK];
        float cmb[CHUNK];
#pragma unroll
        for (int t = 0; t < CHUNK; ++t) {
            const int lr = (ch * CHUNK + t) * 16 + l16;
            cb0[t] = s4[lr * 8 + C0];
            cb1[t] = s4[lr * 8 + C1];
            cmb[t] = smb[lr];
        }
#pragma unroll
        for (int t = 0; t < CHUNK; ++t) {
            bf16x8 bfr0 = *reinterpret_cast<const bf16x8*>(&cb0[t]);
            bf16x8 bfr1 = *reinterpret_cast<const bf16x8*>(&cb1[t]);
            f32x4 acc0 = {cmb[t], cmb[t], cmb[t], cmb[t]};
#pragma unroll
            for (int mt = 0; mt < 4; ++mt) {
                f32x4 acc = acc0;
                acc = __builtin_amdgcn_mfma_f32_16x16x32_bf16(afr[mt][0], bfr0, acc, 0, 0, 0);
                acc = __builtin_amdgcn_mfma_f32_16x16x32_bf16(afr[mt][1], bfr1, acc, 0, 0, 0);
#pragma unroll
                for (int i = 0; i < 4; ++i)
                    pmax[mt * 4 + i] = fmaxf(pmax[mt * 4 + i], acc[i]);
            }
        }
    }

    // butterfly max over the 16 l16-lanes; thresholds (validated margin, /2 in max space)
#pragma unroll
    for (int off = 1; off < 16; off <<= 1)
#pragma unroll
        for (int j = 0; j < 16; ++j) pmax[j] = fmaxf(pmax[j], __shfl_xor(pmax[j], off));
    float trA[16];
#pragma unroll
    for (int mt = 0; mt < 4; ++mt)
#pragma unroll
        for (int i = 0; i < 4; ++i) {
            float Afr = __shfl(af, mt * 16 + lh * 4 + i);
            trA[mt * 4 + i] = pmax[mt * 4 + i]
                            - (sqrtf(Afr) * 1.001f * wmaxv * 0.015625f + 5e-4f);
        }

    // ---- PASS B: candidates (recompute acc'; bitwise == pass A; push acc' >= trA) ----
#pragma unroll 1
    for (int ch = 0; ch < NCH; ++ch) {
        float4 cb0[CHUNK], cb1[CHUNK];
        float cmb[CHUNK];
#pragma unroll
        for (int t = 0; t < CHUNK; ++t) {
            const int lr = (ch * CHUNK + t) * 16 + l16;
            cb0[t] = s4[lr * 8 + C0];
            cb1[t] = s4[lr * 8 + C1];
            cmb[t] = smb[lr];
        }
#pragma unroll
        for (int t = 0; t < CHUNK; ++t) {
            bf16x8 bfr0 = *reinterpret_cast<const bf16x8*>(&cb0[t]);
            bf16x8 bfr1 = *reinterpret_cast<const bf16x8*>(&cb1[t]);
            f32x4 acc0 = {cmb[t], cmb[t], cmb[t], cmb[t]};
            const int kk = (ch * CHUNK + t) * 16 + l16;
#pragma unroll
            for (int mt = 0; mt < 4; ++mt) {
                f32x4 acc = acc0;
                acc = __builtin_amdgcn_mfma_f32_16x16x32_bf16(afr[mt][0], bfr0, acc, 0, 0, 0);
                acc = __builtin_amdgcn_mfma_f32_16x16x32_bf16(afr[mt][1], bfr1, acc, 0, 0, 0);
#pragma unroll
                for (int i = 0; i < 4; ++i) {
                    if (acc[i] >= trA[mt * 4 + i]) {
                        int row = mt * 16 + lh * 4 + i;
                        int slot = atomicAdd(&scnt[wv][row], 1);
                        if (slot < CMAX) sclist[wv][row][slot] = (unsigned short)kk;
                    }
                }
            }
        }
    }
    __builtin_amdgcn_wave_barrier();

    // ---- rescore: lane r owns row r; sequential lexicographic (d,k) min ----
    {
        const int cnt = scnt[wv][lane];
        if (cnt <= CMAX) {
            const size_t ng = rowbase + lane;
            const float* hrow = h + ng * DDIM;
            float hreg[DDIM];
#pragma unroll
            for (int i = 0; i < DDIM; i += 4) {
                float4 v = *reinterpret_cast<const float4*>(hrow + i);
                hreg[i] = v.x; hreg[i + 1] = v.y; hreg[i + 2] = v.z; hreg[i + 3] = v.w;
            }
            float dbest = INFINITY;
            int kbest = 0x7FFFFFFF;
            for (int slot = 0; slot < cnt; ++slot) {
                int k = sclist[wv][lane][slot];
                const float* wr = w + (size_t)k * DDIM;
                float acc = 0.f;
#pragma unroll
                for (int i = 0; i < DDIM; i += 4) {
                    float4 x = *reinterpret_cast<const float4*>(wr + i);
                    acc = fmaf(hreg[i + 0], x.x, acc);
                    acc = fmaf(hreg[i + 1], x.y, acc);
                    acc = fmaf(hreg[i + 2], x.z, acc);
                    acc = fmaf(hreg[i + 3], x.w, acc);
                }
                float d = __fsub_rn(__fadd_rn(af, bsq[k]), __fadd_rn(acc, acc));
                if (d < dbest || (d == dbest && k < kbest)) { dbest = d; kbest = k; }
            }
            sbk[wv][lane] = (unsigned)kbest;
        }
    }
    // overflow fallback: wave-wide exact scan + in-wave lexicographic butterfly (rare)
#pragma unroll 1
    for (int r = 0; r < RPW; ++r) {
        if (scnt[wv][r] > CMAX) {
            const float Afr = __shfl(af, r);
            const size_t ng = rowbase + r;
            const float* hrow = h + ng * DDIM;
            float hreg[DDIM];
#pragma unroll
            for (int i = 0; i < DDIM; i += 4) {
                float4 v = *reinterpret_cast<const float4*>(hrow + i);
                hreg[i] = v.x; hreg[i + 1] = v.y; hreg[i + 2] = v.z; hreg[i + 3] = v.w;
            }
            float dbest = INFINITY;
            int kbest = 0x7FFFFFFF;
            for (int k = lane; k < KCB; k += 64) {
                const float* wr = w + (size_t)k * DDIM;
                float acc = 0.f;
#pragma unroll
                for (int i = 0; i < DDIM; i += 4) {
                    float4 x = *reinterpret_cast<const float4*>(wr + i);
                    acc = fmaf(hreg[i + 0], x.x, acc);
                    acc = fmaf(hreg[i + 1], x.y, acc);
                    acc = fmaf(hreg[i + 2], x.z, acc);
                    acc = fmaf(hreg[i + 3], x.w, acc);
                }
                float d = __fsub_rn(__fadd_rn(Afr, bsq[k]), __fadd_rn(acc, acc));
                if (d < dbest || (d == dbest && k < kbest)) { dbest = d; kbest = k; }
            }
#pragma unroll
            for (int off = 1; off < 64; off <<= 1) {
                float od = __shfl_xor(dbest, off);
                int ok = __shfl_xor(kbest, off);
                bool take = (od < dbest) || (od == dbest && ok < kbest);
                dbest = take ? od : dbest;
                kbest = take ? ok : kbest;
            }
            if (lane == 0) sbk[wv][r] = (unsigned)kbest;
        }
    }
    __builtin_amdgcn_wave_barrier();

    // ---- fused outputs (per wave) — frozen math, R18/R22 lane layout ----
    out[NQ + rowbase + lane] = (float)sbk[wv][lane];

    // qst: 64 rows x 16 float4 = 16 per lane; ops identical to validated K4
#pragma unroll
    for (int q = 0; q < 16; ++q) {
        const int idx = q * 64 + lane;          // 0..1023
        const int row = idx >> 4, c4 = idx & 15;
        const int bk = (int)sbk[wv][row];
        const size_t ng = rowbase + row;
        float4 hq = *reinterpret_cast<const float4*>(h + ng * DDIM + 4 * c4);
        float4 wq = *reinterpret_cast<const float4*>(w + (size_t)bk * DDIM + 4 * c4);
        float4 o;
        o.x = __fadd_rn(hq.x, __fsub_rn(wq.x, hq.x));
        o.y = __fadd_rn(hq.y, __fsub_rn(wq.y, hq.y));
        o.z = __fadd_rn(hq.z, __fsub_rn(wq.z, hq.z));
        o.w = __fadd_rn(hq.w, __fsub_rn(wq.w, hq.w));
        *reinterpret_cast<float4*>(out + ng * DDIM + 4 * c4) = o;
    }

    // loss: all 64 lanes, one row each — verbatim frozen recipe (validated R2)
    {
        const int bk = (int)sbk[wv][lane];
        const size_t ng = rowbase + lane;
        const float* hrow = h + ng * DDIM;
        const float* qrow = w + (size_t)bk * DDIM;
        float hr[DDIM];
#pragma unroll
        for (int i = 0; i < DDIM; i += 4) {
            float4 v = *reinterpret_cast<const float4*>(hrow + i);
            hr[i] = v.x; hr[i + 1] = v.y; hr[i + 2] = v.z; hr[i + 3] = v.w;
        }
        float r2[8];
#pragma unroll
        for (int c = 0; c < 8; ++c) {
            float4 qa = *reinterpret_cast<const float4*>(qrow + 8 * c);
            float4 qb = *reinterpret_cast<const float4*>(qrow + 8 * c + 4);
            float d0 = __fsub_rn(qa.x, hr[8 * c + 0]);
            float d1 = __fsub_rn(qa.y, hr[8 * c + 1]);
            float d2 = __fsub_rn(qa.z, hr[8 * c + 2]);
            float d3 = __fsub_rn(qa.w, hr[8 * c + 3]);
            float d4 = __fsub_rn(qb.x, hr[8 * c + 4]);
            float d5 = __fsub_rn(qb.y, hr[8 * c + 5]);
            float d6 = __fsub_rn(qb.z, hr[8 * c + 6]);
            float d7 = __fsub_rn(qb.w, hr[8 * c + 7]);
            if (c == 0) {
                r2[0] = __fmul_rn(d0, d0); r2[1] = __fmul_rn(d1, d1);
                r2[2] = __fmul_rn(d2, d2); r2[3] = __fmul_rn(d3, d3);
                r2[4] = __fmul_rn(d4, d4); r2[5] = __fmul_rn(d5, d5);
                r2[6] = __fmul_rn(d6, d6); r2[7] = __fmul_rn(d7, d7);
            } else {
                r2[0] = __fadd_rn(r2[0], __fmul_rn(d0, d0));
                r2[1] = __fadd_rn(r2[1], __fmul_rn(d1, d1));
                r2[2] = __fadd_rn(r2[2], __fmul_rn(d2, d2));
                r2[3] = __fadd_rn(r2[3], __fmul_rn(d3, d3));
                r2[4] = __fadd_rn(r2[4], __fmul_rn(d4, d4));
                r2[5] = __fadd_rn(r2[5], __fmul_rn(d5, d5));
                r2[6] = __fadd_rn(r2[6], __fmul_rn(d6, d6));
                r2[7] = __fadd_rn(r2[7], __fmul_rn(d7, d7));
            }
        }
        float S = __fadd_rn(__fadd_rn(__fadd_rn(r2[0], r2[1]), __fadd_rn(r2[2], r2[3])),
                            __fadd_rn(__fadd_rn(r2[4], r2[5]), __fadd_rn(r2[6], r2[7])));
        float m = __fmul_rn(S, 0.015625f);
        out[NQ + NROWS + ng] = __fadd_rn(__fmul_rn(m, 0.1f), __fmul_rn(m, 0.2f));
    }
}

extern "C" void kernel_launch(void* const* d_in, const int* in_sizes, int n_in,
                              void* d_out, int out_size, void* d_ws, size_t ws_size,
                              hipStream_t stream) {
    (void)in_sizes; (void)n_in; (void)out_size; (void)ws_size;
    const float* h = (const float*)d_in[0];
    const float* w = (const float*)d_in[1];
    float* out = (float*)d_out;

    char* ws = (char*)d_ws;
    float* bsq = (float*)ws;                               // 4 KB
    float* wmaxp = (float*)(ws + 4096);                    // 16 B
    unsigned short* wbf = (unsigned short*)(ws + 8192);    // 128 KB

    prep_w<<<1, 1024, 0, stream>>>(w, bsq, wbf, wmaxp);
    vq_scan<<<NBLK, BLKT, 0, stream>>>(h, w, wbf, bsq, wmaxp, out);
}

// Round 24
// 306.460 us; speedup vs baseline: 1.9983x; 1.5519x over previous
//
#include <hip/hip_runtime.h>
#include <math.h>

#define NROWS (512 * 512)
#define KCB   1024
#define DDIM  64
#define NQ    ((size_t)NROWS * DDIM)
#define RPW   32            // rows per group per wave
#define CMAX  8             // candidate cap per row
#define WAVES 16
#define BLKT  1024
#define NBLK  256           // 1 block per CU, persistent
#define ITERS 2             // row-groups per wave: 256*16*2*32 = 262144

typedef __attribute__((ext_vector_type(8))) short bf16x8;
typedef __attribute__((ext_vector_type(4))) float f32x4;

__device__ __forceinline__ unsigned short f2bf(float x) {
    unsigned u = __float_as_uint(x);
    u = u + 0x7FFFu + ((u >> 16) & 1u);
    return (unsigned short)(u >> 16);
}
__device__ __forceinline__ unsigned fsort(float d) {   // monotonic f32 -> u32
    unsigned u = __float_as_uint(d);
    return (u & 0x80000000u) ? ~u : (u | 0x80000000u);
}

// ---------- K1: frozen wsq + w->bf16 + wmax ----------
__global__ __launch_bounds__(1024)
void prep_w(const float* __restrict__ w, float* __restrict__ bsq,
            unsigned short* __restrict__ wbf, float* __restrict__ wmaxp) {
    __shared__ float red[16];
    const int k = threadIdx.x;
    const float* row = w + (size_t)k * DDIM;
    float r[8];
#pragma unroll
    for (int j = 0; j < 8; ++j) r[j] = __fmul_rn(row[j], row[j]);
#pragma unroll
    for (int i = 8; i < DDIM; i += 8)
#pragma unroll
        for (int j = 0; j < 8; ++j)
            r[j] = __fadd_rn(r[j], __fmul_rn(row[i + j], row[i + j]));
    float b = __fadd_rn(__fadd_rn(__fadd_rn(r[0], r[1]), __fadd_rn(r[2], r[3])),
                        __fadd_rn(__fadd_rn(r[4], r[5]), __fadd_rn(r[6], r[7])));
    bsq[k] = b;
    unsigned* dst = (unsigned*)(wbf + (size_t)k * DDIM);
#pragma unroll
    for (int j = 0; j < 32; ++j)
        dst[j] = (unsigned)f2bf(row[2 * j]) | ((unsigned)f2bf(row[2 * j + 1]) << 16);
    float v = sqrtf(b) * 1.02f;
#pragma unroll
    for (int off = 1; off < 64; off <<= 1) v = fmaxf(v, __shfl_xor(v, off));
    if ((threadIdx.x & 63) == 0) red[threadIdx.x >> 6] = v;
    __syncthreads();
    if (threadIdx.x == 0) {
        float m = red[0];
#pragma unroll
        for (int j = 1; j < 16; ++j) m = fmaxf(m, red[j]);
        *wmaxp = m;
    }
}

// ---------- K3: R21 + setprio around MFMA + chunk-loop unroll-2 ----------
__global__ __launch_bounds__(BLKT, 1)
void vq_scan(const float* __restrict__ h, const float* __restrict__ w,
             const unsigned short* __restrict__ wbf, const float* __restrict__ bsq,
             const float* __restrict__ wmaxp, float* __restrict__ out) {
    __shared__ float4 s4[KCB * 8];                       // 131072 B
    __shared__ float smb[KCB];                           //   4096 B: -bsq/2 (scan only)
    __shared__ int scnt[WAVES][RPW];                     //   2048 B
    __shared__ unsigned short sclist[WAVES][RPW][CMAX];  //   8192 B
    __shared__ unsigned long long sbkey[WAVES][RPW];     //   4096 B  => 149504 total

    const int tid = threadIdx.x;
    const int wv = tid >> 6, lane = tid & 63;
    const int l16 = lane & 15, lh = lane >> 4;

    // ---- one-time stage: whole codebook, linear LDS write + inverse-permuted read ----
    {
        const float4* g4 = reinterpret_cast<const float4*>(wbf);
#pragma unroll
        for (int j = 0; j < 8; ++j) {
            int F = j * BLKT + tid;          // 0..8191
            int r = F >> 3, c = F & 7;
            s4[F] = g4[r * 8 + (c ^ (r & 7))];
        }
        smb[tid] = __fmul_rn(bsq[tid], -0.5f);   // C-in value: acc' = dot - bq/2
    }
    __syncthreads();   // the only block barrier

    const int sw = l16 & 7;
    const int C0 = lh ^ sw;         // chunk for d0..31
    const int C1 = (4 + lh) ^ sw;   // chunk for d32..63
    const float wmaxv = *wmaxp;

#pragma unroll 1
    for (int it = 0; it < ITERS; ++it) {
        const size_t rowbase = ((size_t)blockIdx.x * WAVES + wv) * (RPW * ITERS) + (size_t)it * RPW;

        if (lane < RPW) { scnt[wv][lane] = 0; sbkey[wv][lane] = 0xFFFFFFFFFFFFFFFFULL; }

        // Af: frozen pairwise-8 (lane r computes row r)
        float af = 0.f;
        if (lane < RPW) {
            const float* row = h + (size_t)(rowbase + lane) * DDIM;
            float hr[DDIM];
#pragma unroll
            for (int i = 0; i < DDIM; i += 4) {
                float4 v = *reinterpret_cast<const float4*>(row + i);
                hr[i] = v.x; hr[i + 1] = v.y; hr[i + 2] = v.z; hr[i + 3] = v.w;
            }
            float s[8];
#pragma unroll
            for (int j = 0; j < 8; ++j) s[j] = __fmul_rn(hr[j], hr[j]);
#pragma unroll
            for (int i = 8; i < DDIM; i += 8)
#pragma unroll
                for (int j = 0; j < 8; ++j)
                    s[j] = __fadd_rn(s[j], __fmul_rn(hr[i + j], hr[i + j]));
            af = __fadd_rn(__fadd_rn(__fadd_rn(s[0], s[1]), __fadd_rn(s[2], s[3])),
                           __fadd_rn(__fadd_rn(s[4], s[5]), __fadd_rn(s[6], s[7])));
        }

        // A-frags (h rows, bf16) — layout validated R10-R21
        bf16x8 afr[2][2];
#pragma unroll
        for (int mt = 0; mt < 2; ++mt) {
            const float* hrow = h + ((size_t)(rowbase + mt * 16 + l16)) * DDIM;
#pragma unroll
            for (int dh = 0; dh < 2; ++dh) {
                float4 a = *reinterpret_cast<const float4*>(hrow + dh * 32 + lh * 8);
                float4 bq = *reinterpret_cast<const float4*>(hrow + dh * 32 + lh * 8 + 4);
                union { bf16x8 v; unsigned short u[8]; } pk;
                pk.u[0] = f2bf(a.x); pk.u[1] = f2bf(a.y); pk.u[2] = f2bf(a.z); pk.u[3] = f2bf(a.w);
                pk.u[4] = f2bf(bq.x); pk.u[5] = f2bf(bq.y); pk.u[6] = f2bf(bq.z); pk.u[7] = f2bf(bq.w);
                afr[mt][dh] = pk.v;
            }
        }

        // ---- PASS A: max-space; acc' = dot - bq/2 via MFMA C-in; 1 fmax/val ----
        float pmax[8];
#pragma unroll
        for (int j = 0; j < 8; ++j) pmax[j] = -INFINITY;

#pragma unroll 2
        for (int ch = 0; ch < 8; ++ch) {
            float4 cb0[8], cb1[8];
            float cmb[8];
#pragma unroll
            for (int t = 0; t < 8; ++t) {
                const int lr = (ch * 8 + t) * 16 + l16;
                cb0[t] = s4[lr * 8 + C0];
                cb1[t] = s4[lr * 8 + C1];
                cmb[t] = smb[lr];
            }
            __builtin_amdgcn_s_setprio(1);
#pragma unroll
            for (int t = 0; t < 8; ++t) {
                bf16x8 bfr0 = *reinterpret_cast<const bf16x8*>(&cb0[t]);
                bf16x8 bfr1 = *reinterpret_cast<const bf16x8*>(&cb1[t]);
                f32x4 acc0 = {cmb[t], cmb[t], cmb[t], cmb[t]};
#pragma unroll
                for (int mt = 0; mt < 2; ++mt) {
                    f32x4 acc = acc0;
                    acc = __builtin_amdgcn_mfma_f32_16x16x32_bf16(afr[mt][0], bfr0, acc, 0, 0, 0);
                    acc = __builtin_amdgcn_mfma_f32_16x16x32_bf16(afr[mt][1], bfr1, acc, 0, 0, 0);
#pragma unroll
                    for (int i = 0; i < 4; ++i)
                        pmax[mt * 4 + i] = fmaxf(pmax[mt * 4 + i], acc[i]);
                }
            }
            __builtin_amdgcn_s_setprio(0);
        }

        // butterfly max over the 16 l16-lanes; thresholds (validated margin, /2 in max space)
#pragma unroll
        for (int off = 1; off < 16; off <<= 1)
#pragma unroll
            for (int j = 0; j < 8; ++j) pmax[j] = fmaxf(pmax[j], __shfl_xor(pmax[j], off));
        float trA[8];
#pragma unroll
        for (int mt = 0; mt < 2; ++mt)
#pragma unroll
            for (int i = 0; i < 4; ++i) {
                float Afr = __shfl(af, mt * 16 + lh * 4 + i);
                trA[mt * 4 + i] = pmax[mt * 4 + i]
                                - (sqrtf(Afr) * 1.001f * wmaxv * 0.015625f + 5e-4f);
            }

        // ---- PASS B: candidates (recompute acc'; bitwise == pass A; push acc' >= trA) ----
#pragma unroll 2
        for (int ch = 0; ch < 8; ++ch) {
            float4 cb0[8], cb1[8];
            float cmb[8];
#pragma unroll
            for (int t = 0; t < 8; ++t) {
                const int lr = (ch * 8 + t) * 16 + l16;
                cb0[t] = s4[lr * 8 + C0];
                cb1[t] = s4[lr * 8 + C1];
                cmb[t] = smb[lr];
            }
            __builtin_amdgcn_s_setprio(1);
#pragma unroll
            for (int t = 0; t < 8; ++t) {
                bf16x8 bfr0 = *reinterpret_cast<const bf16x8*>(&cb0[t]);
                bf16x8 bfr1 = *reinterpret_cast<const bf16x8*>(&cb1[t]);
                f32x4 acc0 = {cmb[t], cmb[t], cmb[t], cmb[t]};
                const int kk = (ch * 8 + t) * 16 + l16;
#pragma unroll
                for (int mt = 0; mt < 2; ++mt) {
                    f32x4 acc = acc0;
                    acc = __builtin_amdgcn_mfma_f32_16x16x32_bf16(afr[mt][0], bfr0, acc, 0, 0, 0);
                    acc = __builtin_amdgcn_mfma_f32_16x16x32_bf16(afr[mt][1], bfr1, acc, 0, 0, 0);
#pragma unroll
                    for (int i = 0; i < 4; ++i) {
                        if (acc[i] >= trA[mt * 4 + i]) {
                            int row = mt * 16 + lh * 4 + i;
                            int slot = atomicAdd(&scnt[wv][row], 1);
                            if (slot < CMAX) sclist[wv][row][slot] = (unsigned short)kk;
                        }
                    }
                }
            }
            __builtin_amdgcn_s_setprio(0);
        }
        __builtin_amdgcn_wave_barrier();

        // ---- rescore: 2 lanes/row, exact frozen chain, (d,k) atomicMin key ----
        {
            const int row = lane >> 1;
            const int s0 = lane & 1;
            const float Afr = __shfl(af, row);
            const int cnt = scnt[wv][row];
            if (cnt <= CMAX && s0 < cnt) {
                const size_t ng = rowbase + row;
                const float* hrow = h + ng * DDIM;
                float hreg[DDIM];
#pragma unroll
                for (int i = 0; i < DDIM; i += 4) {
                    float4 v = *reinterpret_cast<const float4*>(hrow + i);
                    hreg[i] = v.x; hreg[i + 1] = v.y; hreg[i + 2] = v.z; hreg[i + 3] = v.w;
                }
                for (int slot = s0; slot < cnt; slot += 2) {
                    int k = sclist[wv][row][slot];
                    const float* wr = w + (size_t)k * DDIM;
                    float acc = 0.f;
#pragma unroll
                    for (int i = 0; i < DDIM; i += 4) {
                        float4 x = *reinterpret_cast<const float4*>(wr + i);
                        acc = fmaf(hreg[i + 0], x.x, acc);
                        acc = fmaf(hreg[i + 1], x.y, acc);
                        acc = fmaf(hreg[i + 2], x.z, acc);
                        acc = fmaf(hreg[i + 3], x.w, acc);
                    }
                    float d = __fsub_rn(__fadd_rn(Afr, bsq[k]), __fadd_rn(acc, acc));
                    unsigned long long key = ((unsigned long long)fsort(d) << 32) | (unsigned)k;
                    atomicMin(&sbkey[wv][row], key);
                }
            }
        }
        // overflow fallback (exact full scan, wave-wide; rare)
#pragma unroll 1
        for (int r = 0; r < RPW; ++r) {
            const float Afr = __shfl(af, r);
            if (scnt[wv][r] > CMAX) {
                const size_t ng = rowbase + r;
                const float* hrow = h + ng * DDIM;
                float hreg[DDIM];
#pragma unroll
                for (int i = 0; i < DDIM; i += 4) {
                    float4 v = *reinterpret_cast<const float4*>(hrow + i);
                    hreg[i] = v.x; hreg[i + 1] = v.y; hreg[i + 2] = v.z; hreg[i + 3] = v.w;
                }
                for (int k = lane; k < KCB; k += 64) {
                    const float* wr = w + (size_t)k * DDIM;
                    float acc = 0.f;
#pragma unroll
                    for (int i = 0; i < DDIM; i += 4) {
                        float4 x = *reinterpret_cast<const float4*>(wr + i);
                        acc = fmaf(hreg[i + 0], x.x, acc);
                        acc = fmaf(hreg[i + 1], x.y, acc);
                        acc = fmaf(hreg[i + 2], x.z, acc);
                        acc = fmaf(hreg[i + 3], x.w, acc);
                    }
                    float d = __fsub_rn(__fadd_rn(Afr, bsq[k]), __fadd_rn(acc, acc));
                    unsigned long long key = ((unsigned long long)fsort(d) << 32) | (unsigned)k;
                    atomicMin(&sbkey[wv][r], key);
                }
            }
        }
        __builtin_amdgcn_wave_barrier();

        // ---- fused outputs (per wave) — frozen R13-R21 ----
        if (lane < RPW)
            out[NQ + rowbase + lane] = (float)(unsigned)(sbkey[wv][lane] & 0xFFFFFFFFu);

#pragma unroll
        for (int q = 0; q < 8; ++q) {
            const int idx = q * 64 + lane;
            const int row = idx >> 4, c4 = idx & 15;
            const int bk = (int)(unsigned)(sbkey[wv][row] & 0xFFFFFFFFu);
            const size_t ng = rowbase + row;
            float4 hq = *reinterpret_cast<const float4*>(h + ng * DDIM + 4 * c4);
            float4 wq = *reinterpret_cast<const float4*>(w + (size_t)bk * DDIM + 4 * c4);
            float4 o;
            o.x = __fadd_rn(hq.x, __fsub_rn(wq.x, hq.x));
            o.y = __fadd_rn(hq.y, __fsub_rn(wq.y, hq.y));
            o.z = __fadd_rn(hq.z, __fsub_rn(wq.z, hq.z));
            o.w = __fadd_rn(hq.w, __fsub_rn(wq.w, hq.w));
            *reinterpret_cast<float4*>(out + ng * DDIM + 4 * c4) = o;
        }

        if (lane < RPW) {
            const int bk = (int)(unsigned)(sbkey[wv][lane] & 0xFFFFFFFFu);
            const size_t ng = rowbase + lane;
            const float* hrow = h + ng * DDIM;
            const float* qrow = w + (size_t)bk * DDIM;
            float hr[DDIM];
#pragma unroll
            for (int i = 0; i < DDIM; i += 4) {
                float4 v = *reinterpret_cast<const float4*>(hrow + i);
                hr[i] = v.x; hr[i + 1] = v.y; hr[i + 2] = v.z; hr[i + 3] = v.w;
            }
            float r2[8];
#pragma unroll
            for (int c = 0; c < 8; ++c) {
                float4 qa = *reinterpret_cast<const float4*>(qrow + 8 * c);
                float4 qb = *reinterpret_cast<const float4*>(qrow + 8 * c + 4);
                float d0 = __fsub_rn(qa.x, hr[8 * c + 0]);
                float d1 = __fsub_rn(qa.y, hr[8 * c + 1]);
                float d2 = __fsub_rn(qa.z, hr[8 * c + 2]);
                float d3 = __fsub_rn(qa.w, hr[8 * c + 3]);
                float d4 = __fsub_rn(qb.x, hr[8 * c + 4]);
                float d5 = __fsub_rn(qb.y, hr[8 * c + 5]);
                float d6 = __fsub_rn(qb.z, hr[8 * c + 6]);
                float d7 = __fsub_rn(qb.w, hr[8 * c + 7]);
                if (c == 0) {
                    r2[0] = __fmul_rn(d0, d0); r2[1] = __fmul_rn(d1, d1);
                    r2[2] = __fmul_rn(d2, d2); r2[3] = __fmul_rn(d3, d3);
                    r2[4] = __fmul_rn(d4, d4); r2[5] = __fmul_rn(d5, d5);
                    r2[6] = __fmul_rn(d6, d6); r2[7] = __fmul_rn(d7, d7);
                } else {
                    r2[0] = __fadd_rn(r2[0], __fmul_rn(d0, d0));
                    r2[1] = __fadd_rn(r2[1], __fmul_rn(d1, d1));
                    r2[2] = __fadd_rn(r2[2], __fmul_rn(d2, d2));
                    r2[3] = __fadd_rn(r2[3], __fmul_rn(d3, d3));
                    r2[4] = __fadd_rn(r2[4], __fmul_rn(d4, d4));
                    r2[5] = __fadd_rn(r2[5], __fmul_rn(d5, d5));
                    r2[6] = __fadd_rn(r2[6], __fmul_rn(d6, d6));
                    r2[7] = __fadd_rn(r2[7], __fmul_rn(d7, d7));
                }
            }
            float S = __fadd_rn(__fadd_rn(__fadd_rn(r2[0], r2[1]), __fadd_rn(r2[2], r2[3])),
                                __fadd_rn(__fadd_rn(r2[4], r2[5]), __fadd_rn(r2[6], r2[7])));
            float m = __fmul_rn(S, 0.015625f);
            out[NQ + NROWS + ng] = __fadd_rn(__fmul_rn(m, 0.1f), __fmul_rn(m, 0.2f));
        }
    }
}

extern "C" void kernel_launch(void* const* d_in, const int* in_sizes, int n_in,
                              void* d_out, int out_size, void* d_ws, size_t ws_size,
                              hipStream_t stream) {
    (void)in_sizes; (void)n_in; (void)out_size; (void)ws_size;
    const float* h = (const float*)d_in[0];
    const float* w = (const float*)d_in[1];
    float* out = (float*)d_out;

    char* ws = (char*)d_ws;
    float* bsq = (float*)ws;                               // 4 KB
    float* wmaxp = (float*)(ws + 4096);                    // 16 B
    unsigned short* wbf = (unsigned short*)(ws + 8192);    // 128 KB

    prep_w<<<1, 1024, 0, stream>>>(w, bsq, wbf, wmaxp);
    vq_scan<<<NBLK, BLKT, 0, stream>>>(h, w, wbf, bsq, wmaxp, out);
}

// Round 25
// 262.291 us; speedup vs baseline: 2.3348x; 1.1684x over previous
//
#include <hip/hip_runtime.h>
#include <math.h>

#define NROWS (512 * 512)
#define KCB   1024
#define DDIM  64
#define NQ    ((size_t)NROWS * DDIM)
#define RPW   32            // rows per group per wave
#define CMAX  8             // candidate cap per row
#define WAVES 16
#define BLKT  1024
#define NBLK  256           // 1 block per CU, persistent
#define ITERS 2             // row-groups per wave: 256*16*2*32 = 262144

typedef __attribute__((ext_vector_type(8))) short bf16x8;
typedef __attribute__((ext_vector_type(4))) float f32x4;

__device__ __forceinline__ unsigned short f2bf(float x) {
    unsigned u = __float_as_uint(x);
    u = u + 0x7FFFu + ((u >> 16) & 1u);
    return (unsigned short)(u >> 16);
}
__device__ __forceinline__ unsigned fsort(float d) {   // monotonic f32 -> u32
    unsigned u = __float_as_uint(d);
    return (u & 0x80000000u) ? ~u : (u | 0x80000000u);
}

// ---------- K1: frozen wsq + w->bf16 + wmax ----------
__global__ __launch_bounds__(1024)
void prep_w(const float* __restrict__ w, float* __restrict__ bsq,
            unsigned short* __restrict__ wbf, float* __restrict__ wmaxp) {
    __shared__ float red[16];
    const int k = threadIdx.x;
    const float* row = w + (size_t)k * DDIM;
    float r[8];
#pragma unroll
    for (int j = 0; j < 8; ++j) r[j] = __fmul_rn(row[j], row[j]);
#pragma unroll
    for (int i = 8; i < DDIM; i += 8)
#pragma unroll
        for (int j = 0; j < 8; ++j)
            r[j] = __fadd_rn(r[j], __fmul_rn(row[i + j], row[i + j]));
    float b = __fadd_rn(__fadd_rn(__fadd_rn(r[0], r[1]), __fadd_rn(r[2], r[3])),
                        __fadd_rn(__fadd_rn(r[4], r[5]), __fadd_rn(r[6], r[7])));
    bsq[k] = b;
    unsigned* dst = (unsigned*)(wbf + (size_t)k * DDIM);
#pragma unroll
    for (int j = 0; j < 32; ++j)
        dst[j] = (unsigned)f2bf(row[2 * j]) | ((unsigned)f2bf(row[2 * j + 1]) << 16);
    float v = sqrtf(b) * 1.02f;
#pragma unroll
    for (int off = 1; off < 64; off <<= 1) v = fmaxf(v, __shfl_xor(v, off));
    if ((threadIdx.x & 63) == 0) red[threadIdx.x >> 6] = v;
    __syncthreads();
    if (threadIdx.x == 0) {
        float m = red[0];
#pragma unroll
        for (int j = 1; j < 16; ++j) m = fmaxf(m, red[j]);
        *wmaxp = m;
    }
}

// ---------- K3: persistent 1024-thread blocks (4 waves/SIMD), codebook in LDS ----------
__global__ __launch_bounds__(BLKT, 1)
void vq_scan(const float* __restrict__ h, const float* __restrict__ w,
             const unsigned short* __restrict__ wbf, const float* __restrict__ bsq,
             const float* __restrict__ wmaxp, float* __restrict__ out) {
    // full codebook, swizzled: row lr (0..1023) x 8 float4 chunks;
    // chunk c stored at s4[lr*8 + (c ^ (lr&7))]  (XOR involution, 16B granularity)
    __shared__ float4 s4[KCB * 8];                       // 131072 B
    __shared__ float sbsq[KCB];                          //   4096 B
    __shared__ int scnt[WAVES][RPW];                     //   2048 B
    __shared__ unsigned short sclist[WAVES][RPW][CMAX];  //   8192 B
    __shared__ unsigned long long sbkey[WAVES][RPW];     //   4096 B  => 149504 total

    const int tid = threadIdx.x;
    const int wv = tid >> 6, lane = tid & 63;
    const int l16 = lane & 15, lh = lane >> 4;

    // ---- one-time stage: whole codebook, linear LDS write + inverse-permuted read ----
    {
        const float4* g4 = reinterpret_cast<const float4*>(wbf);
#pragma unroll
        for (int j = 0; j < 8; ++j) {
            int F = j * BLKT + tid;          // 0..8191
            int r = F >> 3, c = F & 7;
            s4[F] = g4[r * 8 + (c ^ (r & 7))];
        }
        sbsq[tid] = bsq[tid];
    }
    __syncthreads();   // the only block barrier

    // per-lane constant swizzled chunk indices (lr ≡ l16 mod 8)
    const int sw = l16 & 7;
    const int C0 = lh ^ sw;         // chunk for d0..31
    const int C1 = (4 + lh) ^ sw;   // chunk for d32..63
    const float wmaxv = *wmaxp;

#pragma unroll 1
    for (int it = 0; it < ITERS; ++it) {
        const size_t rowbase = ((size_t)blockIdx.x * WAVES + wv) * (RPW * ITERS) + (size_t)it * RPW;

        if (lane < RPW) { scnt[wv][lane] = 0; sbkey[wv][lane] = 0xFFFFFFFFFFFFFFFFULL; }

        // Af: frozen pairwise-8 (lane r computes row r)
        float af = 0.f;
        if (lane < RPW) {
            const float* row = h + (size_t)(rowbase + lane) * DDIM;
            float hr[DDIM];
#pragma unroll
            for (int i = 0; i < DDIM; i += 4) {
                float4 v = *reinterpret_cast<const float4*>(row + i);
                hr[i] = v.x; hr[i + 1] = v.y; hr[i + 2] = v.z; hr[i + 3] = v.w;
            }
            float s[8];
#pragma unroll
            for (int j = 0; j < 8; ++j) s[j] = __fmul_rn(hr[j], hr[j]);
#pragma unroll
            for (int i = 8; i < DDIM; i += 8)
#pragma unroll
                for (int j = 0; j < 8; ++j)
                    s[j] = __fadd_rn(s[j], __fmul_rn(hr[i + j], hr[i + j]));
            af = __fadd_rn(__fadd_rn(__fadd_rn(s[0], s[1]), __fadd_rn(s[2], s[3])),
                           __fadd_rn(__fadd_rn(s[4], s[5]), __fadd_rn(s[6], s[7])));
        }

        // A-frags (h rows, bf16) — layout validated R10-R19
        bf16x8 afr[2][2];
#pragma unroll
        for (int mt = 0; mt < 2; ++mt) {
            const float* hrow = h + ((size_t)(rowbase + mt * 16 + l16)) * DDIM;
#pragma unroll
            for (int dh = 0; dh < 2; ++dh) {
                float4 a = *reinterpret_cast<const float4*>(hrow + dh * 32 + lh * 8);
                float4 bq = *reinterpret_cast<const float4*>(hrow + dh * 32 + lh * 8 + 4);
                union { bf16x8 v; unsigned short u[8]; } pk;
                pk.u[0] = f2bf(a.x); pk.u[1] = f2bf(a.y); pk.u[2] = f2bf(a.z); pk.u[3] = f2bf(a.w);
                pk.u[4] = f2bf(bq.x); pk.u[5] = f2bf(bq.y); pk.u[6] = f2bf(bq.z); pk.u[7] = f2bf(bq.w);
                afr[mt][dh] = pk.v;
            }
        }

        // ---- PASS A: mins; 8 chunks x (16 ds_read_b128 issued wide, then 16 MFMA) ----
        float pmin[8];
#pragma unroll
        for (int j = 0; j < 8; ++j) pmin[j] = INFINITY;

#pragma unroll 1
        for (int ch = 0; ch < 8; ++ch) {
            float4 cb0[8], cb1[8];
            float cbq[8];
#pragma unroll
            for (int t = 0; t < 8; ++t) {
                const int lr = (ch * 8 + t) * 16 + l16;
                cb0[t] = s4[lr * 8 + C0];
                cb1[t] = s4[lr * 8 + C1];
                cbq[t] = sbsq[lr];
            }
#pragma unroll
            for (int t = 0; t < 8; ++t) {
                bf16x8 bfr0 = *reinterpret_cast<const bf16x8*>(&cb0[t]);
                bf16x8 bfr1 = *reinterpret_cast<const bf16x8*>(&cb1[t]);
#pragma unroll
                for (int mt = 0; mt < 2; ++mt) {
                    f32x4 acc = {0.f, 0.f, 0.f, 0.f};
                    acc = __builtin_amdgcn_mfma_f32_16x16x32_bf16(afr[mt][0], bfr0, acc, 0, 0, 0);
                    acc = __builtin_amdgcn_mfma_f32_16x16x32_bf16(afr[mt][1], bfr1, acc, 0, 0, 0);
#pragma unroll
                    for (int i = 0; i < 4; ++i)
                        pmin[mt * 4 + i] = fminf(pmin[mt * 4 + i], cbq[t] - (acc[i] + acc[i]));
                }
            }
        }

        // butterfly min over the 16 l16-lanes; thresholds (validated margin formula)
#pragma unroll
        for (int off = 1; off < 16; off <<= 1)
#pragma unroll
            for (int j = 0; j < 8; ++j) pmin[j] = fminf(pmin[j], __shfl_xor(pmin[j], off));
        float tr[8];
#pragma unroll
        for (int mt = 0; mt < 2; ++mt)
#pragma unroll
            for (int i = 0; i < 4; ++i) {
                float Afr = __shfl(af, mt * 16 + lh * 4 + i);
                tr[mt * 4 + i] = pmin[mt * 4 + i] + sqrtf(Afr) * 1.001f * wmaxv * 0.03125f + 1e-3f;
            }

        // ---- PASS B: candidates (recompute from resident LDS; bitwise == pass A) ----
#pragma unroll 1
        for (int ch = 0; ch < 8; ++ch) {
            float4 cb0[8], cb1[8];
            float cbq[8];
#pragma unroll
            for (int t = 0; t < 8; ++t) {
                const int lr = (ch * 8 + t) * 16 + l16;
                cb0[t] = s4[lr * 8 + C0];
                cb1[t] = s4[lr * 8 + C1];
                cbq[t] = sbsq[lr];
            }
#pragma unroll
            for (int t = 0; t < 8; ++t) {
                bf16x8 bfr0 = *reinterpret_cast<const bf16x8*>(&cb0[t]);
                bf16x8 bfr1 = *reinterpret_cast<const bf16x8*>(&cb1[t]);
                const int kk = (ch * 8 + t) * 16 + l16;
#pragma unroll
                for (int mt = 0; mt < 2; ++mt) {
                    f32x4 acc = {0.f, 0.f, 0.f, 0.f};
                    acc = __builtin_amdgcn_mfma_f32_16x16x32_bf16(afr[mt][0], bfr0, acc, 0, 0, 0);
                    acc = __builtin_amdgcn_mfma_f32_16x16x32_bf16(afr[mt][1], bfr1, acc, 0, 0, 0);
#pragma unroll
                    for (int i = 0; i < 4; ++i) {
                        float val = cbq[t] - (acc[i] + acc[i]);
                        if (val <= tr[mt * 4 + i]) {
                            int row = mt * 16 + lh * 4 + i;
                            int slot = atomicAdd(&scnt[wv][row], 1);
                            if (slot < CMAX) sclist[wv][row][slot] = (unsigned short)kk;
                        }
                    }
                }
            }
        }
        __builtin_amdgcn_wave_barrier();

        // ---- rescore: 2 lanes/row, exact frozen chain, (d,k) atomicMin key ----
        {
            const int row = lane >> 1;
            const int s0 = lane & 1;
            const float Afr = __shfl(af, row);
            const int cnt = scnt[wv][row];
            if (cnt <= CMAX && s0 < cnt) {
                const size_t ng = rowbase + row;
                const float* hrow = h + ng * DDIM;
                float hreg[DDIM];
#pragma unroll
                for (int i = 0; i < DDIM; i += 4) {
                    float4 v = *reinterpret_cast<const float4*>(hrow + i);
                    hreg[i] = v.x; hreg[i + 1] = v.y; hreg[i + 2] = v.z; hreg[i + 3] = v.w;
                }
                for (int slot = s0; slot < cnt; slot += 2) {
                    int k = sclist[wv][row][slot];
                    const float* wr = w + (size_t)k * DDIM;
                    float acc = 0.f;
#pragma unroll
                    for (int i = 0; i < DDIM; i += 4) {
                        float4 x = *reinterpret_cast<const float4*>(wr + i);
                        acc = fmaf(hreg[i + 0], x.x, acc);
                        acc = fmaf(hreg[i + 1], x.y, acc);
                        acc = fmaf(hreg[i + 2], x.z, acc);
                        acc = fmaf(hreg[i + 3], x.w, acc);
                    }
                    float d = __fsub_rn(__fadd_rn(Afr, bsq[k]), __fadd_rn(acc, acc));
                    unsigned long long key = ((unsigned long long)fsort(d) << 32) | (unsigned)k;
                    atomicMin(&sbkey[wv][row], key);
                }
            }
        }
        // overflow fallback (exact full scan, wave-wide; rare)
#pragma unroll 1
        for (int r = 0; r < RPW; ++r) {
            const float Afr = __shfl(af, r);
            if (scnt[wv][r] > CMAX) {
                const size_t ng = rowbase + r;
                const float* hrow = h + ng * DDIM;
                float hreg[DDIM];
#pragma unroll
                for (int i = 0; i < DDIM; i += 4) {
                    float4 v = *reinterpret_cast<const float4*>(hrow + i);
                    hreg[i] = v.x; hreg[i + 1] = v.y; hreg[i + 2] = v.z; hreg[i + 3] = v.w;
                }
                for (int k = lane; k < KCB; k += 64) {
                    const float* wr = w + (size_t)k * DDIM;
                    float acc = 0.f;
#pragma unroll
                    for (int i = 0; i < DDIM; i += 4) {
                        float4 x = *reinterpret_cast<const float4*>(wr + i);
                        acc = fmaf(hreg[i + 0], x.x, acc);
                        acc = fmaf(hreg[i + 1], x.y, acc);
                        acc = fmaf(hreg[i + 2], x.z, acc);
                        acc = fmaf(hreg[i + 3], x.w, acc);
                    }
                    float d = __fsub_rn(__fadd_rn(Afr, bsq[k]), __fadd_rn(acc, acc));
                    unsigned long long key = ((unsigned long long)fsort(d) << 32) | (unsigned)k;
                    atomicMin(&sbkey[wv][r], key);
                }
            }
        }
        __builtin_amdgcn_wave_barrier();

        // ---- fused outputs (per wave) — frozen R13-R19 ----
        if (lane < RPW)
            out[NQ + rowbase + lane] = (float)(unsigned)(sbkey[wv][lane] & 0xFFFFFFFFu);

#pragma unroll
        for (int q = 0; q < 8; ++q) {
            const int idx = q * 64 + lane;
            const int row = idx >> 4, c4 = idx & 15;
            const int bk = (int)(unsigned)(sbkey[wv][row] & 0xFFFFFFFFu);
            const size_t ng = rowbase + row;
            float4 hq = *reinterpret_cast<const float4*>(h + ng * DDIM + 4 * c4);
            float4 wq = *reinterpret_cast<const float4*>(w + (size_t)bk * DDIM + 4 * c4);
            float4 o;
            o.x = __fadd_rn(hq.x, __fsub_rn(wq.x, hq.x));
            o.y = __fadd_rn(hq.y, __fsub_rn(wq.y, hq.y));
            o.z = __fadd_rn(hq.z, __fsub_rn(wq.z, hq.z));
            o.w = __fadd_rn(hq.w, __fsub_rn(wq.w, hq.w));
            *reinterpret_cast<float4*>(out + ng * DDIM + 4 * c4) = o;
        }

        if (lane < RPW) {
            const int bk = (int)(unsigned)(sbkey[wv][lane] & 0xFFFFFFFFu);
            const size_t ng = rowbase + lane;
            const float* hrow = h + ng * DDIM;
            const float* qrow = w + (size_t)bk * DDIM;
            float hr[DDIM];
#pragma unroll
            for (int i = 0; i < DDIM; i += 4) {
                float4 v = *reinterpret_cast<const float4*>(hrow + i);
                hr[i] = v.x; hr[i + 1] = v.y; hr[i + 2] = v.z; hr[i + 3] = v.w;
            }
            float r2[8];
#pragma unroll
            for (int c = 0; c < 8; ++c) {
                float4 qa = *reinterpret_cast<const float4*>(qrow + 8 * c);
                float4 qb = *reinterpret_cast<const float4*>(qrow + 8 * c + 4);
                float d0 = __fsub_rn(qa.x, hr[8 * c + 0]);
                float d1 = __fsub_rn(qa.y, hr[8 * c + 1]);
                float d2 = __fsub_rn(qa.z, hr[8 * c + 2]);
                float d3 = __fsub_rn(qa.w, hr[8 * c + 3]);
                float d4 = __fsub_rn(qb.x, hr[8 * c + 4]);
                float d5 = __fsub_rn(qb.y, hr[8 * c + 5]);
                float d6 = __fsub_rn(qb.z, hr[8 * c + 6]);
                float d7 = __fsub_rn(qb.w, hr[8 * c + 7]);
                if (c == 0) {
                    r2[0] = __fmul_rn(d0, d0); r2[1] = __fmul_rn(d1, d1);
                    r2[2] = __fmul_rn(d2, d2); r2[3] = __fmul_rn(d3, d3);
                    r2[4] = __fmul_rn(d4, d4); r2[5] = __fmul_rn(d5, d5);
                    r2[6] = __fmul_rn(d6, d6); r2[7] = __fmul_rn(d7, d7);
                } else {
                    r2[0] = __fadd_rn(r2[0], __fmul_rn(d0, d0));
                    r2[1] = __fadd_rn(r2[1], __fmul_rn(d1, d1));
                    r2[2] = __fadd_rn(r2[2], __fmul_rn(d2, d2));
                    r2[3] = __fadd_rn(r2[3], __fmul_rn(d3, d3));
                    r2[4] = __fadd_rn(r2[4], __fmul_rn(d4, d4));
                    r2[5] = __fadd_rn(r2[5], __fmul_rn(d5, d5));
                    r2[6] = __fadd_rn(r2[6], __fmul_rn(d6, d6));
                    r2[7] = __fadd_rn(r2[7], __fmul_rn(d7, d7));
                }
            }
            float S = __fadd_rn(__fadd_rn(__fadd_rn(r2[0], r2[1]), __fadd_rn(r2[2], r2[3])),
                                __fadd_rn(__fadd_rn(r2[4], r2[5]), __fadd_rn(r2[6], r2[7])));
            float m = __fmul_rn(S, 0.015625f);
            out[NQ + NROWS + ng] = __fadd_rn(__fmul_rn(m, 0.1f), __fmul_rn(m, 0.2f));
        }
    }
}

extern "C" void kernel_launch(void* const* d_in, const int* in_sizes, int n_in,
                              void* d_out, int out_size, void* d_ws, size_t ws_size,
                              hipStream_t stream) {
    (void)in_sizes; (void)n_in; (void)out_size; (void)ws_size;
    const float* h = (const float*)d_in[0];
    const float* w = (const float*)d_in[1];
    float* out = (float*)d_out;

    char* ws = (char*)d_ws;
    float* bsq = (float*)ws;                               // 4 KB
    float* wmaxp = (float*)(ws + 4096);                    // 16 B
    unsigned short* wbf = (unsigned short*)(ws + 8192);    // 128 KB

    prep_w<<<1, 1024, 0, stream>>>(w, bsq, wbf, wmaxp);
    vq_scan<<<NBLK, BLKT, 0, stream>>>(h, w, wbf, bsq, wmaxp, out);
}